// Round 5
// baseline (179.475 us; speedup 1.0000x reference)
//
#include <hip/hip_runtime.h>

#define VQ_K 512
#define VQ_D 64
#define VQ_N (32 * 64 * 64)   // B*H*W = 131072
#define CH_STRIDE 4096        // H*W
#define B_STRIDE  262144      // C*H*W
#define KSPLIT 4
#define KPW (VQ_K / KSPLIT)   // 128 codes per wave

typedef float f32x8 __attribute__((ext_vector_type(8)));

// Pre-pass: squared norms of codebook rows into workspace.
__global__ void cb_sqr_kernel(const float* __restrict__ cb,
                              float* __restrict__ cbsq) {
    int k = blockIdx.x * blockDim.x + threadIdx.x;
    if (k < VQ_K) {
        float s = 0.f;
        #pragma unroll
        for (int d = 0; d < VQ_D; ++d) {
            float v = cb[k * VQ_D + d];
            s = fmaf(v, v, s);
        }
        cbsq[k] = s;
    }
}

// Block = 256 threads = 64 positions x 4 k-groups (wave w scans codes
// [w*128, w*128+128)).
// R3/R4 post-mortem: launch_bounds/waves_per_eu only CAP registers; the RA
// still targets 8 waves/SIMD (<=64 VGPR) and spills x around the pin
// (~4.3 GB cache reload traffic ~= the measured 127us). Fix: pad static LDS
// to 40KB/block -> hard occupancy cap 4 blocks/CU = 4 waves/SIMD -> the RA's
// own budget becomes 512/4 = 128 VGPR, so keeping x resident (~90 regs) is
// strictly cheaper than spilling. LDS is the occupancy channel the compiler
// actually respects.
__global__ __launch_bounds__(256) void vq_argmin_kernel(
        const float* __restrict__ x,
        const float* __restrict__ cb,
        const float* __restrict__ cbsq,
        int* __restrict__ out) {
    // 40960 B total static LDS: pad + reduce buffers.
    __shared__ float pad[9728];           // 38912 B, kept alive below
    __shared__ float sbest[KSPLIT][64];   // 1024 B
    __shared__ int   sbi[KSPLIT][64];     // 1024 B

    int t   = threadIdx.x;
    int pos = t & 63;                                     // position in block
    int w   = __builtin_amdgcn_readfirstlane(t >> 6);     // wave id, uniform
    int n   = blockIdx.x * 64 + pos;
    int b   = n >> 12;        // / 4096 (64 | 4096: whole block in same batch)
    int p   = n & 4095;       // h*64 + w
    const float* xb = x + b * B_STRIDE + p;

    // Load the 64-dim vector once (coalesced across lanes per channel) into
    // 8 float8 tuples, then pin them in VGPRs with ONE opaque asm statement.
    f32x8 vv[8];
    #pragma unroll
    for (int c = 0; c < 8; ++c) {
        #pragma unroll
        for (int j = 0; j < 8; ++j)
            vv[c][j] = xb[(c * 8 + j) * CH_STRIDE];
    }
    asm volatile("" : "+v"(vv[0]), "+v"(vv[1]), "+v"(vv[2]), "+v"(vv[3]),
                      "+v"(vv[4]), "+v"(vv[5]), "+v"(vv[6]), "+v"(vv[7]));

    // ||x||^2 in fp32, 4 accumulators (same association as R1-R4, absmax 0.0).
    float s0 = 0.f, s1 = 0.f, s2 = 0.f, s3 = 0.f;
    #pragma unroll
    for (int c = 0; c < 8; ++c) {
        s0 = fmaf(vv[c][0], vv[c][0], s0);
        s1 = fmaf(vv[c][1], vv[c][1], s1);
        s2 = fmaf(vv[c][2], vv[c][2], s2);
        s3 = fmaf(vv[c][3], vv[c][3], s3);
        s0 = fmaf(vv[c][4], vv[c][4], s0);
        s1 = fmaf(vv[c][5], vv[c][5], s1);
        s2 = fmaf(vv[c][6], vv[c][6], s2);
        s3 = fmaf(vv[c][7], vv[c][7], s3);
    }
    float insq = (s0 + s1) + (s2 + s3);

    float best = 3.4e38f;
    int bi = 0;
    const float* rowbase = cb + w * (KPW * VQ_D);
    const float* sqbase  = cbsq + w * KPW;
    for (int kk = 0; kk < KPW; ++kk) {
        const float* row = rowbase + kk * VQ_D;   // uniform -> s_load_dwordx16
        float d0 = 0.f, d1 = 0.f, d2 = 0.f, d3 = 0.f;
        #pragma unroll
        for (int c = 0; c < 8; ++c) {
            d0 = fmaf(vv[c][0], row[c * 8 + 0], d0);
            d1 = fmaf(vv[c][1], row[c * 8 + 1], d1);
            d2 = fmaf(vv[c][2], row[c * 8 + 2], d2);
            d3 = fmaf(vv[c][3], row[c * 8 + 3], d3);
            d0 = fmaf(vv[c][4], row[c * 8 + 4], d0);
            d1 = fmaf(vv[c][5], row[c * 8 + 5], d1);
            d2 = fmaf(vv[c][6], row[c * 8 + 6], d2);
            d3 = fmaf(vv[c][7], row[c * 8 + 7], d3);
        }
        float dot  = (d0 + d1) + (d2 + d3);
        float dist = (insq + sqbase[kk]) - 2.f * dot;
        if (dist < best) { best = dist; bi = w * KPW + kk; }  // strict <
    }

    // Keep the 38KB pad allocated: branch on a runtime value the compiler
    // can't fold away (grid is 2048, but it can't know that).
    if (blockIdx.x + 1u == 0u) pad[t] = best;

    // Cross-wave argmin reduce via LDS, ascending k-group order with
    // strict < preserves np.argmin first-occurrence tie-breaking.
    sbest[w][pos] = best;
    sbi[w][pos]   = bi;
    __syncthreads();
    if (t < 64) {
        float bb = sbest[0][t];
        int   ii = sbi[0][t];
        #pragma unroll
        for (int j = 1; j < KSPLIT; ++j) {
            float c = sbest[j][t];
            if (c < bb) { bb = c; ii = sbi[j][t]; }
        }
        out[blockIdx.x * 64 + t] = ii;
    }
}

extern "C" void kernel_launch(void* const* d_in, const int* in_sizes, int n_in,
                              void* d_out, int out_size, void* d_ws, size_t ws_size,
                              hipStream_t stream) {
    const float* x  = (const float*)d_in[0];   // [32,64,64,64] fp32
    const float* cb = (const float*)d_in[1];   // [512,64] fp32
    int* out = (int*)d_out;                    // [32,64,64] int32
    float* cbsq = (float*)d_ws;                // 512 floats scratch

    cb_sqr_kernel<<<1, VQ_K, 0, stream>>>(cb, cbsq);
    vq_argmin_kernel<<<VQ_N / 64, 256, 0, stream>>>(x, cb, cbsq, out);
}